// Round 9
// baseline (482.076 us; speedup 1.0000x reference)
//
#include <hip/hip_runtime.h>
#include <hip/hip_cooperative_groups.h>
#include <hip/hip_bf16.h>
#include <math.h>

namespace cg = cooperative_groups;

#define B_ 2
#define T_ 2048
#define C_ 1024
#define H_ 16
#define D_ 64
#define M_ (B_ * T_)   // 4096
#define K_ 1024

// 0.125 * log2(e): folds the 1/sqrt(64) softmax scale into exp2-domain
#define SCALE2 0.18033688011112043f

typedef short bf16x8 __attribute__((ext_vector_type(8)));
typedef float f32x4  __attribute__((ext_vector_type(4)));
typedef unsigned int u32;

// LDS geometry shared by all phases (sum = 49536 B -> 3 blocks/CU)
#define AS0_SZ (128 * 32 + 64)    // + prep-tile pad (64x65 shorts = 8320 B)
#define BUF_SZ (128 * 32)         // 8192 B
#define BS2_SZ (128 * 32 + 128)   // + bias tail (2112 floats = 8448 B)

__device__ __forceinline__ unsigned short f2b(float f) {
    __hip_bfloat16 h = __float2bfloat16(f);
    return *reinterpret_cast<unsigned short*>(&h);
}
// pack hi16(a),hi16(b) -> dword [b_hi:a_hi] with round-half-up (+0x8000)
__device__ __forceinline__ u32 pack_bf16_rnd(float a, float b) {
    const u32 au = __float_as_uint(a) + 0x8000u;
    const u32 bu = __float_as_uint(b) + 0x8000u;
    return __builtin_amdgcn_perm(bu, au, 0x07060302u);
}
__device__ __forceinline__ void load_lds16(const void* g, void* l) {
    __builtin_amdgcn_global_load_lds(
        (const __attribute__((address_space(1))) u32*)g,
        (__attribute__((address_space(3))) u32*)l, 16, 0, 0);
}
// K/V LDS swizzle (R8, measured): 64x64 shorts, 16B-slot XOR
__device__ __forceinline__ int kv_swz(int row, int col8) {
    return row * 64 + ((col8 ^ ((row ^ (row >> 2)) & 7)) * 8);   // shorts
}

// ---------------------------------------------------------------------------
// prep unit (shared by fused phase 1 and legacy kernel):
//   u <  2048 : convert x fp32 -> bf16
//   u <  3072 : convert + transpose W[z] (64x64 tiles; stride-65 LDS tile —
//               odd stride makes the 8 scalar column-reads conflict-free:
//               bank=((kc+e)*65+nc)>>1 mod 32, kc*65===kc mod 64 -> distinct)
//   else      : distance-bias table (exp2 domain) + rotary trig table
// ---------------------------------------------------------------------------
__device__ __forceinline__ void prep_unit(
    int u, int tid, unsigned short (*tile)[65],
    const float* __restrict__ x,
    const float* __restrict__ W0, const float* __restrict__ W1,
    const float* __restrict__ W2, const float* __restrict__ W3,
    const float* __restrict__ tbl,
    unsigned short* __restrict__ xb,
    unsigned short* __restrict__ T0, unsigned short* __restrict__ T1,
    unsigned short* __restrict__ T2, unsigned short* __restrict__ T3,
    float* __restrict__ dtab, float2* __restrict__ trig)
{
    if (u < 2048) {
        const int idx = u * 256 + tid;
        const float4 a = reinterpret_cast<const float4*>(x)[idx * 2];
        const float4 b = reinterpret_cast<const float4*>(x)[idx * 2 + 1];
        unsigned short t[8] = {f2b(a.x), f2b(a.y), f2b(a.z), f2b(a.w),
                               f2b(b.x), f2b(b.y), f2b(b.z), f2b(b.w)};
        reinterpret_cast<bf16x8*>(xb)[idx] = *reinterpret_cast<const bf16x8*>(t);
    } else if (u < 3072) {
        const int w = u - 2048;                // 0..1023
        const int z = w >> 8;                  // which W
        const int rem = w & 255;
        const int k0 = (rem & 15) * 64, n0 = (rem >> 4) * 64;
        const float* W = z == 0 ? W0 : z == 1 ? W1 : z == 2 ? W2 : W3;
        unsigned short* Wt = z == 0 ? T0 : z == 1 ? T1 : z == 2 ? T2 : T3;

        #pragma unroll
        for (int it = 0; it < 4; ++it) {
            const int idx = it * 256 + tid;
            const int r = idx >> 4, c = (idx & 15) * 4;
            const float4 w4 = *reinterpret_cast<const float4*>(W + (size_t)(k0 + r) * C_ + n0 + c);
            tile[r][c + 0] = f2b(w4.x); tile[r][c + 1] = f2b(w4.y);
            tile[r][c + 2] = f2b(w4.z); tile[r][c + 3] = f2b(w4.w);
        }
        __syncthreads();
        #pragma unroll
        for (int it = 0; it < 2; ++it) {
            const int idx = it * 256 + tid;
            const int nc = idx >> 3, kc = (idx & 7) * 8;
            unsigned short tmp[8];
            #pragma unroll
            for (int e = 0; e < 8; ++e) tmp[e] = tile[kc + e][nc];
            *reinterpret_cast<bf16x8*>(Wt + (size_t)(n0 + nc) * K_ + k0 + kc) =
                *reinterpret_cast<const bf16x8*>(tmp);
        }
        __syncthreads();   // tile reusable by next unit
    } else {
        const int idx = (u - 3072) * 256 + tid;   // 0..65535
        if (idx < H_ * T_) {
            const int h = idx >> 11, n = idx & (T_ - 1);
            int bucket;
            if (n < 16) bucket = n;
            else {
                int vb = 16 + (int)(log2f((float)n * 0.0625f) * (16.0f / 3.0f));
                bucket = vb < 31 ? vb : 31;
            }
            dtab[idx] = tbl[bucket * H_ + h] * SCALE2;
        }
        const int t = idx >> 5, j = idx & 31;
        const float inv = exp2f(-(float)j * (13.287712379549449f / 32.0f));
        const float ang = (float)t * inv;
        trig[idx] = make_float2(cosf(ang), sinf(ang));
    }
}

// ---------------------------------------------------------------------------
// MFMA GEMM core, 128x128 tile (R5 counted-vmcnt 3-buffer pipeline, frozen).
// LDS buffers passed in (distinct static objects at every call site -> DMA
// alias analysis stays precise after forced inlining).
// mode 0: fp32 row-major [M,C]; mode 1: rotary+scatter bf16 (Q,K);
// mode 2: bf16 V^T packed b64 stores (V)
// ---------------------------------------------------------------------------
__device__ __forceinline__ void gemm_core128(
    unsigned short* __restrict__ As0, unsigned short* __restrict__ As1,
    unsigned short* __restrict__ As2, unsigned short* __restrict__ Bs0,
    unsigned short* __restrict__ Bs1, unsigned short* __restrict__ Bs2,
    const unsigned short* __restrict__ A, const unsigned short* __restrict__ Bt,
    const float* __restrict__ bias, const float2* __restrict__ trig,
    float rot_scale, float* __restrict__ outf,
    unsigned short* __restrict__ outb, int mode, int m0, int n0)
{
    const int tid = threadIdx.x;
    const int wid = tid >> 6, lane = tid & 63;
    const int l16 = lane & 15, quad = lane >> 4;
    const int wm = wid >> 1, wn = wid & 1;

    f32x4 acc[4][4];
    #pragma unroll
    for (int i = 0; i < 4; ++i)
        #pragma unroll
        for (int j = 0; j < 4; ++j) acc[i][j] = (f32x4){0.f, 0.f, 0.f, 0.f};

    auto stage = [&](unsigned short* Asb, unsigned short* Bsb, int k0) {
        #pragma unroll
        for (int it = 0; it < 2; ++it) {
            const int idx = it * 256 + tid;
            const int row = idx >> 2, ch = (idx & 3) * 8;
            load_lds16(A + (size_t)(m0 + row) * K_ + k0 + ch,
                       (char*)Asb + it * 4096 + wid * 1024);
            load_lds16(Bt + (size_t)(n0 + row) * K_ + k0 + ch,
                       (char*)Bsb + it * 4096 + wid * 1024);
        }
    };
    auto compute = [&](const unsigned short* Asb, const unsigned short* Bsb) {
        bf16x8 af[4], bf[4];
        #pragma unroll
        for (int i = 0; i < 4; ++i) {
            af[i] = *reinterpret_cast<const bf16x8*>(&Asb[(wm * 64 + i * 16 + l16) * 32 + quad * 8]);
            bf[i] = *reinterpret_cast<const bf16x8*>(&Bsb[(wn * 64 + i * 16 + l16) * 32 + quad * 8]);
        }
        #pragma unroll
        for (int i = 0; i < 4; ++i)
            #pragma unroll
            for (int j = 0; j < 4; ++j)
                acc[i][j] = __builtin_amdgcn_mfma_f32_16x16x32_bf16(af[i], bf[j], acc[i][j], 0, 0, 0);
    };
    auto step = [&](const unsigned short* cA, const unsigned short* cB,
                    unsigned short* nA, unsigned short* nB, int kn, bool do_stage) {
        asm volatile("s_waitcnt vmcnt(4)" ::: "memory");
        __builtin_amdgcn_s_barrier();
        __builtin_amdgcn_sched_barrier(0);
        if (do_stage) stage(nA, nB, kn);
        compute(cA, cB);
    };

    stage(As0, Bs0, 0);
    stage(As1, Bs1, 32);

    for (int kb = 0; kb < 30; kb += 3) {
        step(As0, Bs0, As2, Bs2, (kb + 2) * 32, true);
        step(As1, Bs1, As0, Bs0, (kb + 3) * 32, true);
        step(As2, Bs2, As1, Bs1, (kb + 4) * 32, true);
    }
    step(As0, Bs0, As2, Bs2, 0, false);
    asm volatile("s_waitcnt vmcnt(0)" ::: "memory");
    __builtin_amdgcn_s_barrier();
    __builtin_amdgcn_sched_barrier(0);
    compute(As1, Bs1);

    if (mode == 1) {
        #pragma unroll
        for (int i = 0; i < 4; ++i) {
            const int mb = m0 + wm * 64 + i * 16 + quad * 4;
            const int bb = mb >> 11, tb = mb & (T_ - 1);
            #pragma unroll
            for (int jc = 0; jc < 2; ++jc) {
                const int n_lo = n0 + wn * 64 + jc * 16 + l16;
                const int h = n_lo >> 6, d = n_lo & 63;     // d < 32
                const float bv_lo = bias[n_lo], bv_hi = bias[n_lo + 32];
                unsigned short* po = outb + (((size_t)bb * H_ + h) * T_ + tb) * D_ + d;
                #pragma unroll
                for (int r = 0; r < 4; ++r) {
                    const float2 cs = trig[(tb + r) * 32 + d];
                    const float a = acc[i][jc][r] + bv_lo;
                    const float b = acc[i][jc + 2][r] + bv_hi;
                    po[(size_t)r * D_]      = f2b((a * cs.x - b * cs.y) * rot_scale);
                    po[(size_t)r * D_ + 32] = f2b((b * cs.x + a * cs.y) * rot_scale);
                }
            }
        }
        return;
    }

    #pragma unroll
    for (int i = 0; i < 4; ++i) {
        const int mb = m0 + wm * 64 + i * 16 + quad * 4;
        #pragma unroll
        for (int j = 0; j < 4; ++j) {
            const int n = n0 + wn * 64 + j * 16 + l16;
            const float bv = bias[n];
            if (mode == 2) {
                const int bb = mb >> 11, t = mb & (T_ - 1);
                const int h = n >> 6, d = n & 63;
                uint2 w;
                w.x = pack_bf16_rnd(acc[i][j][0] + bv, acc[i][j][1] + bv);
                w.y = pack_bf16_rnd(acc[i][j][2] + bv, acc[i][j][3] + bv);
                *reinterpret_cast<uint2*>(
                    outb + (((size_t)bb * H_ + h) * D_ + d) * T_ + t) = w;
            } else {
                #pragma unroll
                for (int r = 0; r < 4; ++r)
                    outf[(size_t)(mb + r) * C_ + n] = acc[i][j][r] + bv;
            }
        }
    }
}

// ---------------------------------------------------------------------------
// Flash attention body (R8 structure: swizzled K/V dbuf, one barrier/tile,
// bias in MFMA acc init, uniform pairing, setprio, raw v_exp_f32).
// LDS overlaid on the gemm buffers: K dbuf = As0/As1, V dbuf = As2/Bs0,
// Ps = Bs1 (64-stride + 16B-slot XOR swizzle, fits 8 KB, <=2-way banks),
// bias_ls = Bs2 (2112 floats = 8448 B exact).
// ---------------------------------------------------------------------------
__device__ __forceinline__ void flash_body(
    int lin,
    unsigned short* __restrict__ As0, unsigned short* __restrict__ As1,
    unsigned short* __restrict__ As2, unsigned short* __restrict__ Bs0,
    unsigned short* __restrict__ Bs1, unsigned short* __restrict__ Bs2,
    const unsigned short* __restrict__ Q, const unsigned short* __restrict__ K,
    const unsigned short* __restrict__ Vt, const float* __restrict__ dtab,
    unsigned short* __restrict__ Y)
{
    float* bias_ls = reinterpret_cast<float*>(Bs2);

    const int bh  = lin & 31;
    const int rem = lin >> 5;
    const int h = bh & (H_ - 1), b = bh >> 4;
    const int tid = threadIdx.x;
    const int wid = tid >> 6, lane = tid & 63;
    const int l16 = lane & 15, quad = lane >> 4;
    const size_t base = (size_t)bh * T_ * D_;
    const size_t vbase = (size_t)bh * D_ * T_;

    const int qta = (rem + bh) & 15;
    const int qtb = 31 - qta;

    if (tid < 64) bias_ls[tid] = -INFINITY;
    for (int ii = tid; ii < qtb * 64 + 64; ii += 256) bias_ls[64 + ii] = dtab[h * T_ + ii];

    bf16x8 ones;
    #pragma unroll
    for (int e = 0; e < 8; ++e) ones[e] = (short)0x3F80;   // bf16 1.0

    // staging coordinates + swizzled LDS offsets (hoisted)
    const int sr0 = tid >> 3,         sc80 = tid & 7;
    const int sr1 = (tid + 256) >> 3, sc81 = (tid + 256) & 7;
    const int wo0 = kv_swz(sr0, sc80), wo1 = kv_swz(sr1, sc81);
    const int sch0 = sc80 * 8, sch1 = sc81 * 8;

    int kro[4][2], vro[4][2];
    #pragma unroll
    for (int c = 0; c < 4; ++c)
        #pragma unroll
        for (int s = 0; s < 2; ++s) {
            kro[c][s] = kv_swz(l16 * 4 + c, s * 4 + quad);
            vro[c][s] = kv_swz(c * 16 + l16, s * 4 + quad);
        }

    // Ps offsets (per-wave 1024 shorts in Bs1; row stride 64, slot XOR)
    unsigned short* PsW = Bs1 + wid * 1024;
    int pwo[4], pro[2];
    #pragma unroll
    for (int r = 0; r < 4; ++r) {
        const int row = quad * 4 + r;
        pwo[r] = row * 64 + (((l16 >> 1) ^ (row & 7)) << 3) + ((l16 & 1) << 2);
    }
    #pragma unroll
    for (int s = 0; s < 2; ++s)
        pro[s] = l16 * 64 + (((s * 4 + quad) ^ (l16 & 7)) << 3);

    bf16x8 kr[2], vr[2];
    kr[0] = *reinterpret_cast<const bf16x8*>(K + base + (size_t)sr0 * D_ + sch0);
    kr[1] = *reinterpret_cast<const bf16x8*>(K + base + (size_t)sr1 * D_ + sch1);
    vr[0] = *reinterpret_cast<const bf16x8*>(Vt + vbase + (size_t)sr0 * T_ + sch0);
    vr[1] = *reinterpret_cast<const bf16x8*>(Vt + vbase + (size_t)sr1 * T_ + sch1);
    *reinterpret_cast<bf16x8*>(&As0[wo0]) = kr[0];
    *reinterpret_cast<bf16x8*>(&As0[wo1]) = kr[1];
    *reinterpret_cast<bf16x8*>(&As2[wo0]) = vr[0];
    *reinterpret_cast<bf16x8*>(&As2[wo1]) = vr[1];
    kr[0] = *reinterpret_cast<const bf16x8*>(K + base + (size_t)(64 + sr0) * D_ + sch0);
    kr[1] = *reinterpret_cast<const bf16x8*>(K + base + (size_t)(64 + sr1) * D_ + sch1);
    vr[0] = *reinterpret_cast<const bf16x8*>(Vt + vbase + (size_t)sr0 * T_ + 64 + sch0);
    vr[1] = *reinterpret_cast<const bf16x8*>(Vt + vbase + (size_t)sr1 * T_ + 64 + sch1);
    __syncthreads();

    int t = 0;   // global tile counter, 0..32
    for (int qi = 0; qi < 2; ++qi) {
        const int qt = qi ? qta : qtb;
        const int q0 = qt * 64;
        const int arow = q0 + wid * 16 + l16;
        const int crow = q0 + wid * 16 + quad * 4;
        const int nbase = crow - l16 * 4;

        bf16x8 qf[2];
        qf[0] = *reinterpret_cast<const bf16x8*>(Q + base + (size_t)arow * D_ + quad * 8);
        qf[1] = *reinterpret_cast<const bf16x8*>(Q + base + (size_t)arow * D_ + 32 + quad * 8);

        f32x4 o[4], ol;
        #pragma unroll
        for (int c = 0; c < 4; ++c) o[c] = (f32x4){0.f, 0.f, 0.f, 0.f};
        ol = (f32x4){0.f, 0.f, 0.f, 0.f};

        for (int kt = 0; kt <= qt; ++kt, ++t) {
            const int j0 = kt * 64;
            const int cur = t & 1;
            const unsigned short* Kc = cur ? As1 : As0;
            unsigned short*       Kn = cur ? As0 : As1;
            const unsigned short* Vc = cur ? Bs0 : As2;
            unsigned short*       Vn = cur ? As2 : Bs0;

            if (t < 32) {
                *reinterpret_cast<bf16x8*>(&Kn[wo0]) = kr[0];
                *reinterpret_cast<bf16x8*>(&Kn[wo1]) = kr[1];
                *reinterpret_cast<bf16x8*>(&Vn[wo0]) = vr[0];
                *reinterpret_cast<bf16x8*>(&Vn[wo1]) = vr[1];
            }
            if (t < 31) {
                const int tn = t + 2;
                const int jn = (tn <= qtb ? tn : tn - qtb - 1) * 64;
                kr[0] = *reinterpret_cast<const bf16x8*>(K + base + (size_t)(jn + sr0) * D_ + sch0);
                kr[1] = *reinterpret_cast<const bf16x8*>(K + base + (size_t)(jn + sr1) * D_ + sch1);
                vr[0] = *reinterpret_cast<const bf16x8*>(Vt + vbase + (size_t)sr0 * T_ + jn + sch0);
                vr[1] = *reinterpret_cast<const bf16x8*>(Vt + vbase + (size_t)sr1 * T_ + jn + sch1);
            }

            const int d0 = nbase - j0;
            const f32x4 blo = *reinterpret_cast<const f32x4*>(&bias_ls[60 + d0]);
            const f32x4 bhi = *reinterpret_cast<const f32x4*>(&bias_ls[64 + d0]);

            f32x4 sc[4];
            #pragma unroll
            for (int c = 0; c < 4; ++c) {
                #pragma unroll
                for (int r = 0; r < 4; ++r)
                    sc[c][r] = (r >= c) ? bhi[r - c] : blo[4 + r - c];
            }
            __builtin_amdgcn_s_setprio(1);
            #pragma unroll
            for (int c = 0; c < 4; ++c) {
                #pragma unroll
                for (int s = 0; s < 2; ++s) {
                    bf16x8 kf = *reinterpret_cast<const bf16x8*>(&Kc[kro[c][s]]);
                    sc[c] = __builtin_amdgcn_mfma_f32_16x16x32_bf16(qf[s], kf, sc[c], 0, 0, 0);
                }
            }
            __builtin_amdgcn_s_setprio(0);

            #pragma unroll
            for (int r = 0; r < 4; ++r) {
                const float p0 = __builtin_amdgcn_exp2f(sc[0][r]);
                const float p1 = __builtin_amdgcn_exp2f(sc[1][r]);
                const float p2 = __builtin_amdgcn_exp2f(sc[2][r]);
                const float p3 = __builtin_amdgcn_exp2f(sc[3][r]);
                uint2 w;
                w.x = pack_bf16_rnd(p0, p1);
                w.y = pack_bf16_rnd(p2, p3);
                *reinterpret_cast<uint2*>(PsW + pwo[r]) = w;
            }

            __builtin_amdgcn_s_setprio(1);
            #pragma unroll
            for (int s = 0; s < 2; ++s) {
                bf16x8 pf = *reinterpret_cast<const bf16x8*>(PsW + pro[s]);
                #pragma unroll
                for (int c = 0; c < 4; ++c) {
                    bf16x8 vf = *reinterpret_cast<const bf16x8*>(&Vc[vro[c][s]]);
                    o[c] = __builtin_amdgcn_mfma_f32_16x16x32_bf16(pf, vf, o[c], 0, 0, 0);
                }
                ol = __builtin_amdgcn_mfma_f32_16x16x32_bf16(pf, ones, ol, 0, 0, 0);
            }
            __builtin_amdgcn_s_setprio(0);

            __syncthreads();   // single barrier per tile
        }

        #pragma unroll
        for (int r = 0; r < 4; ++r) {
            const int i = crow + r;
            const float invl = 1.0f / ol[r];
            #pragma unroll
            for (int c = 0; c < 4; ++c)
                Y[((size_t)b * T_ + i) * C_ + h * D_ + c * 16 + l16] = f2b(o[c][r] * invl);
        }
    }
}

// ---------------------------------------------------------------------------
// Fused cooperative kernel: 768 blocks x 256 threads, 3 blocks/CU resident.
// prep (grid-stride 3328) -> sync -> qkv (768) -> sync -> flash (512)
// -> sync -> proj (256). Eliminates 3 kernel-launch/drain boundaries.
// ---------------------------------------------------------------------------
__global__ __launch_bounds__(256, 3) void fused(
    const float* x, const float* Wq, const float* bq, const float* Wk,
    const float* bk, const float* Wv, const float* bv, const float* Wp,
    const float* bp, const float* tbl,
    unsigned short* xb, unsigned short* Wqt, unsigned short* Wkt,
    unsigned short* Wvt, unsigned short* Wpt,
    unsigned short* Qb, unsigned short* Kb, unsigned short* Vtb,
    unsigned short* Yb, float* dtab, float2* trig, float* out)
{
    __shared__ __align__(16) unsigned short As0[AS0_SZ];
    __shared__ __align__(16) unsigned short As1[BUF_SZ];
    __shared__ __align__(16) unsigned short As2[BUF_SZ];
    __shared__ __align__(16) unsigned short Bs0[BUF_SZ];
    __shared__ __align__(16) unsigned short Bs1[BUF_SZ];
    __shared__ __align__(16) unsigned short Bs2[BS2_SZ];

    const int bid = (int)blockIdx.x;
    const int tid = (int)threadIdx.x;
    cg::grid_group grid = cg::this_grid();

    // ---- phase 1: prep ----
    for (int u = bid; u < 3328; u += 768)
        prep_unit(u, tid, reinterpret_cast<unsigned short(*)[65]>(As0),
                  x, Wq, Wk, Wv, Wp, tbl, xb, Wqt, Wkt, Wvt, Wpt, dtab, trig);
    grid.sync();

    // ---- phase 2: qkv (XCD-grouped decode, 768 units) ----
    {
        const int g = bid & 7, slot = bid >> 3;
        const int w = g * 96 + slot;
        const int z = w >> 8, rem = w & 255;
        const int m0 = (rem >> 3) * 128, n0 = (rem & 7) * 128;
        const unsigned short* Bt = z == 0 ? Wqt : z == 1 ? Wkt : Wvt;
        const float* bias = z == 0 ? bq : z == 1 ? bk : bv;
        unsigned short* outb = z == 0 ? Qb : z == 1 ? Kb : Vtb;
        const float rs = z == 0 ? SCALE2 : 1.0f;
        gemm_core128(As0, As1, As2, Bs0, Bs1, Bs2,
                     xb, Bt, bias, trig, rs, nullptr, outb, z == 2 ? 2 : 1, m0, n0);
    }
    grid.sync();

    // ---- phase 3: flash (512 units; per-CU 2 active + 1 idle) ----
    if (bid < 512)
        flash_body(bid, As0, As1, As2, Bs0, Bs1, Bs2, Qb, Kb, Vtb, dtab, Yb);
    grid.sync();

    // ---- phase 4: proj (256 units; 1 active/CU, XCD-grouped) ----
    if (bid < 256) {
        const int g = bid & 7, slot = bid >> 3;
        const int w = g * 32 + slot;
        const int m0 = (w >> 3) * 128, n0 = (w & 7) * 128;
        gemm_core128(As0, As1, As2, Bs0, Bs1, Bs2,
                     Yb, Wpt, bp, nullptr, 1.0f, out, nullptr, 0, m0, n0);
    }
}

// ---------------------------------------------------------------------------
// Legacy 4-kernel fallback (same bodies) — used if cooperative launch fails.
// ---------------------------------------------------------------------------
__global__ __launch_bounds__(256) void prep_k(
    const float* __restrict__ x,
    const float* __restrict__ W0, const float* __restrict__ W1,
    const float* __restrict__ W2, const float* __restrict__ W3,
    const float* __restrict__ tbl,
    unsigned short* __restrict__ xb,
    unsigned short* __restrict__ T0, unsigned short* __restrict__ T1,
    unsigned short* __restrict__ T2, unsigned short* __restrict__ T3,
    float* __restrict__ dtab, float2* __restrict__ trig)
{
    __shared__ __align__(16) unsigned short tile[64][65];
    prep_unit((int)blockIdx.x, (int)threadIdx.x, tile,
              x, W0, W1, W2, W3, tbl, xb, T0, T1, T2, T3, dtab, trig);
}

__global__ __launch_bounds__(256) void gemm_qkv_k(
    const unsigned short* __restrict__ A,
    const unsigned short* __restrict__ Wq, const unsigned short* __restrict__ Wk,
    const unsigned short* __restrict__ Wv,
    const float* __restrict__ bq, const float* __restrict__ bk,
    const float* __restrict__ bv, const float2* __restrict__ trig,
    unsigned short* __restrict__ Qo, unsigned short* __restrict__ Ko,
    unsigned short* __restrict__ Vto)
{
    __shared__ __align__(16) unsigned short As0[BUF_SZ];
    __shared__ __align__(16) unsigned short As1[BUF_SZ];
    __shared__ __align__(16) unsigned short As2[BUF_SZ];
    __shared__ __align__(16) unsigned short Bs0[BUF_SZ];
    __shared__ __align__(16) unsigned short Bs1[BUF_SZ];
    __shared__ __align__(16) unsigned short Bs2[BUF_SZ];
    const int lin = (int)blockIdx.x;
    const int g = lin & 7, slot = lin >> 3;
    const int w = g * 96 + slot;
    const int z = w >> 8, rem = w & 255;
    const int m0 = (rem >> 3) * 128, n0 = (rem & 7) * 128;
    const unsigned short* Bt = z == 0 ? Wq : z == 1 ? Wk : Wv;
    const float* bias = z == 0 ? bq : z == 1 ? bk : bv;
    unsigned short* outb = z == 0 ? Qo : z == 1 ? Ko : Vto;
    const float rs = z == 0 ? SCALE2 : 1.0f;
    gemm_core128(As0, As1, As2, Bs0, Bs1, Bs2,
                 A, Bt, bias, trig, rs, nullptr, outb, z == 2 ? 2 : 1, m0, n0);
}

__global__ __launch_bounds__(256) void gemm_proj_k(
    const unsigned short* __restrict__ A, const unsigned short* __restrict__ Bt,
    const float* __restrict__ bias, float* __restrict__ outf)
{
    __shared__ __align__(16) unsigned short As0[BUF_SZ];
    __shared__ __align__(16) unsigned short As1[BUF_SZ];
    __shared__ __align__(16) unsigned short As2[BUF_SZ];
    __shared__ __align__(16) unsigned short Bs0[BUF_SZ];
    __shared__ __align__(16) unsigned short Bs1[BUF_SZ];
    __shared__ __align__(16) unsigned short Bs2[BUF_SZ];
    const int lin = (int)blockIdx.x;
    const int g = lin & 7, slot = lin >> 3;
    const int w = g * 32 + slot;
    const int m0 = (w >> 3) * 128, n0 = (w & 7) * 128;
    gemm_core128(As0, As1, As2, Bs0, Bs1, Bs2,
                 A, Bt, bias, nullptr, 1.0f, outf, nullptr, 0, m0, n0);
}

__global__ __launch_bounds__(256) void flash_attn_k(
    const unsigned short* __restrict__ Q, const unsigned short* __restrict__ K,
    const unsigned short* __restrict__ Vt, const float* __restrict__ dtab,
    unsigned short* __restrict__ Y)
{
    __shared__ __align__(16) unsigned short As0[BUF_SZ];
    __shared__ __align__(16) unsigned short As1[BUF_SZ];
    __shared__ __align__(16) unsigned short As2[BUF_SZ];
    __shared__ __align__(16) unsigned short Bs0[BUF_SZ];
    __shared__ __align__(16) unsigned short Bs1[BUF_SZ];
    __shared__ __align__(16) unsigned short Bs2[BS2_SZ];
    const int lin = (int)(blockIdx.y * gridDim.x + blockIdx.x);
    flash_body(lin, As0, As1, As2, Bs0, Bs1, Bs2, Q, K, Vt, dtab, Y);
}

// ---------------------------------------------------------------------------
extern "C" void kernel_launch(void* const* d_in, const int* in_sizes, int n_in,
                              void* d_out, int out_size, void* d_ws, size_t ws_size,
                              hipStream_t stream)
{
    const float* x   = (const float*)d_in[0];
    const float* Wq  = (const float*)d_in[1];
    const float* bq  = (const float*)d_in[2];
    const float* Wk  = (const float*)d_in[3];
    const float* bk  = (const float*)d_in[4];
    const float* Wv  = (const float*)d_in[5];
    const float* bv  = (const float*)d_in[6];
    const float* Wp  = (const float*)d_in[7];
    const float* bp  = (const float*)d_in[8];
    const float* tbl = (const float*)d_in[9];
    float* out = (float*)d_out;

    const size_t n1 = (size_t)B_ * H_ * T_ * D_;       // 4,194,304
    const size_t nW = (size_t)C_ * C_;                 // 1,048,576
    unsigned short* xb  = (unsigned short*)d_ws;       // 8 MB
    unsigned short* Wqt = xb + (size_t)M_ * K_;        // 2 MB each
    unsigned short* Wkt = Wqt + nW;
    unsigned short* Wvt = Wkt + nW;
    unsigned short* Wpt = Wvt + nW;
    unsigned short* Qb  = Wpt + nW;                    // 8 MB each
    unsigned short* Kb  = Qb + n1;
    unsigned short* Vtb = Kb + n1;                     // V^T
    unsigned short* Yb  = Vtb + n1;
    float* dtab = (float*)(Yb + n1);                   // 128 KB
    float2* trig = (float2*)(dtab + H_ * T_);          // 512 KB

    void* args[] = {
        (void*)&x, (void*)&Wq, (void*)&bq, (void*)&Wk, (void*)&bk,
        (void*)&Wv, (void*)&bv, (void*)&Wp, (void*)&bp, (void*)&tbl,
        (void*)&xb, (void*)&Wqt, (void*)&Wkt, (void*)&Wvt, (void*)&Wpt,
        (void*)&Qb, (void*)&Kb, (void*)&Vtb, (void*)&Yb,
        (void*)&dtab, (void*)&trig, (void*)&out };

    hipError_t e = hipLaunchCooperativeKernel(
        (const void*)fused, dim3(768), dim3(256), args, 0, stream);

    if (e != hipSuccess) {
        (void)hipGetLastError();   // clear; fall back to the 4-kernel path
        const dim3 blk(256);
        prep_k<<<dim3(3328), blk, 0, stream>>>(x, Wq, Wk, Wv, Wp, tbl,
                                               xb, Wqt, Wkt, Wvt, Wpt, dtab, trig);
        gemm_qkv_k<<<dim3(768), blk, 0, stream>>>(
            xb, Wqt, Wkt, Wvt, bq, bk, bv, trig, Qb, Kb, Vtb);
        flash_attn_k<<<dim3(16, B_ * H_), blk, 0, stream>>>(Qb, Kb, Vtb, dtab, Yb);
        gemm_proj_k<<<dim3(256), blk, 0, stream>>>(Yb, Wpt, bp, out);
    }
}

// Round 10
// 188.312 us; speedup vs baseline: 2.5600x; 2.5600x over previous
//
#include <hip/hip_runtime.h>
#include <hip/hip_bf16.h>
#include <math.h>

#define B_ 2
#define T_ 2048
#define C_ 1024
#define H_ 16
#define D_ 64
#define M_ (B_ * T_)   // 4096
#define K_ 1024

// 0.125 * log2(e): folds the 1/sqrt(64) softmax scale into exp2-domain
#define SCALE2 0.18033688011112043f

typedef short bf16x8 __attribute__((ext_vector_type(8)));
typedef float f32x4  __attribute__((ext_vector_type(4)));
typedef unsigned int u32;

__device__ __forceinline__ unsigned short f2b(float f) {
    __hip_bfloat16 h = __float2bfloat16(f);
    return *reinterpret_cast<unsigned short*>(&h);
}
// pack hi16(a),hi16(b) -> dword [b_hi:a_hi] with round-half-up (+0x8000)
__device__ __forceinline__ u32 pack_bf16_rnd(float a, float b) {
    const u32 au = __float_as_uint(a) + 0x8000u;
    const u32 bu = __float_as_uint(b) + 0x8000u;
    return __builtin_amdgcn_perm(bu, au, 0x07060302u);
}
__device__ __forceinline__ void load_lds16(const void* g, void* l) {
    __builtin_amdgcn_global_load_lds(
        (const __attribute__((address_space(1))) u32*)g,
        (__attribute__((address_space(3))) u32*)l, 16, 0, 0);
}

// ---------------------------------------------------------------------------
// Merged prep kernel (one launch instead of three):
//   bx <  2048 : convert x fp32 -> bf16
//   bx <  3072 : convert + transpose W[z] (64x64 tiles)
//   else       : distance-bias table (exp2 domain) + rotary trig table
// ---------------------------------------------------------------------------
__global__ __launch_bounds__(256) void prep(
    const float* __restrict__ x,
    const float* __restrict__ W0, const float* __restrict__ W1,
    const float* __restrict__ W2, const float* __restrict__ W3,
    const float* __restrict__ tbl,
    unsigned short* __restrict__ xb,
    unsigned short* __restrict__ T0, unsigned short* __restrict__ T1,
    unsigned short* __restrict__ T2, unsigned short* __restrict__ T3,
    float* __restrict__ dtab, float2* __restrict__ trig)
{
    __shared__ __align__(16) unsigned short tile[64][72];
    const int bx = blockIdx.x;
    const int tid = threadIdx.x;

    if (bx < 2048) {
        const int idx = bx * 256 + tid;
        const float4 a = reinterpret_cast<const float4*>(x)[idx * 2];
        const float4 b = reinterpret_cast<const float4*>(x)[idx * 2 + 1];
        unsigned short t[8] = {f2b(a.x), f2b(a.y), f2b(a.z), f2b(a.w),
                               f2b(b.x), f2b(b.y), f2b(b.z), f2b(b.w)};
        reinterpret_cast<bf16x8*>(xb)[idx] = *reinterpret_cast<const bf16x8*>(t);
    } else if (bx < 3072) {
        const int w = bx - 2048;               // 0..1023
        const int z = w >> 8;                  // which W
        const int rem = w & 255;
        const int k0 = (rem & 15) * 64, n0 = (rem >> 4) * 64;
        const float* W = z == 0 ? W0 : z == 1 ? W1 : z == 2 ? W2 : W3;
        unsigned short* Wt = z == 0 ? T0 : z == 1 ? T1 : z == 2 ? T2 : T3;

        #pragma unroll
        for (int it = 0; it < 4; ++it) {
            const int idx = it * 256 + tid;
            const int r = idx >> 4, c = (idx & 15) * 4;
            const float4 w4 = *reinterpret_cast<const float4*>(W + (size_t)(k0 + r) * C_ + n0 + c);
            tile[r][c + 0] = f2b(w4.x); tile[r][c + 1] = f2b(w4.y);
            tile[r][c + 2] = f2b(w4.z); tile[r][c + 3] = f2b(w4.w);
        }
        __syncthreads();
        #pragma unroll
        for (int it = 0; it < 2; ++it) {
            const int idx = it * 256 + tid;
            const int nc = idx >> 3, kc = (idx & 7) * 8;
            unsigned short tmp[8];
            #pragma unroll
            for (int e = 0; e < 8; ++e) tmp[e] = tile[kc + e][nc];
            *reinterpret_cast<bf16x8*>(Wt + (size_t)(n0 + nc) * K_ + k0 + kc) =
                *reinterpret_cast<const bf16x8*>(tmp);
        }
    } else {
        const int idx = (bx - 3072) * 256 + tid;   // 0..65535
        if (idx < H_ * T_) {
            const int h = idx >> 11, n = idx & (T_ - 1);
            int bucket;
            if (n < 16) bucket = n;
            else {
                int vb = 16 + (int)(log2f((float)n * 0.0625f) * (16.0f / 3.0f));
                bucket = vb < 31 ? vb : 31;
            }
            dtab[idx] = tbl[bucket * H_ + h] * SCALE2;
        }
        const int t = idx >> 5, j = idx & 31;
        // inv_freq = 10000^{-j/32} = 2^{-j*log2(10000)/32}
        const float inv = exp2f(-(float)j * (13.287712379549449f / 32.0f));
        const float ang = (float)t * inv;
        trig[idx] = make_float2(cosf(ang), sinf(ang));
    }
}

// ---------------------------------------------------------------------------
// MFMA GEMM core (R5, frozen): counted-vmcnt 3-buffer pipeline (T4).
// Per step: s_waitcnt vmcnt(NLD) -> s_barrier -> sched_barrier(0) ->
// stage(buf[(s+2)%3]) -> ds_read buf[s%3] + MFMA. Distinct static buffers,
// compile-time indexed (10x3 unroll + 2 tail).
// mode 0: fp32 row-major [M,C] to outf
// mode 1: rotary applied in registers, bf16 scatter to [B,H,T,D] (Q,K)
// mode 2: bf16 V^T [B,H,D,T] packed b64 stores (V)
// ---------------------------------------------------------------------------
template<int BN>
__device__ __forceinline__ void gemm_core(
    const unsigned short* __restrict__ A, const unsigned short* __restrict__ Bt,
    const float* __restrict__ bias, const float2* __restrict__ trig,
    float rot_scale, float* __restrict__ outf,
    unsigned short* __restrict__ outb, int mode, int m0, int n0)
{
    constexpr int FN  = BN / 32;    // n-frags per wave (4 for BN=128, 2 for BN=64)
    constexpr int BCH = BN / 64;    // B stage chunks per thread
    constexpr int NLD = 2 + BCH;    // global_load_lds per thread per stage
    __shared__ __align__(16) unsigned short As0[128 * 32];
    __shared__ __align__(16) unsigned short As1[128 * 32];
    __shared__ __align__(16) unsigned short As2[128 * 32];
    __shared__ __align__(16) unsigned short Bs0[BN * 32];
    __shared__ __align__(16) unsigned short Bs1[BN * 32];
    __shared__ __align__(16) unsigned short Bs2[BN * 32];

    const int tid = threadIdx.x;
    const int wid = tid >> 6, lane = tid & 63;
    const int l16 = lane & 15, quad = lane >> 4;
    const int wm = wid >> 1, wn = wid & 1;

    f32x4 acc[4][FN];
    #pragma unroll
    for (int i = 0; i < 4; ++i)
        #pragma unroll
        for (int j = 0; j < FN; ++j) acc[i][j] = (f32x4){0.f, 0.f, 0.f, 0.f};

    // global_load_lds: LDS dest = wave-uniform base + lane*16 (HW constraint)
    auto stage = [&](unsigned short* Asb, unsigned short* Bsb, int k0) {
        #pragma unroll
        for (int it = 0; it < 2; ++it) {
            const int idx = it * 256 + tid;
            const int row = idx >> 2, ch = (idx & 3) * 8;
            load_lds16(A + (size_t)(m0 + row) * K_ + k0 + ch,
                       (char*)Asb + it * 4096 + wid * 1024);
        }
        #pragma unroll
        for (int it = 0; it < BCH; ++it) {
            const int idx = it * 256 + tid;
            const int row = idx >> 2, ch = (idx & 3) * 8;
            load_lds16(Bt + (size_t)(n0 + row) * K_ + k0 + ch,
                       (char*)Bsb + it * 4096 + wid * 1024);
        }
    };
    auto compute = [&](const unsigned short* Asb, const unsigned short* Bsb) {
        bf16x8 af[4], bf[FN];
        #pragma unroll
        for (int i = 0; i < 4; ++i)
            af[i] = *reinterpret_cast<const bf16x8*>(&Asb[(wm * 64 + i * 16 + l16) * 32 + quad * 8]);
        #pragma unroll
        for (int j = 0; j < FN; ++j)
            bf[j] = *reinterpret_cast<const bf16x8*>(&Bsb[(wn * (BN / 2) + j * 16 + l16) * 32 + quad * 8]);
        #pragma unroll
        for (int i = 0; i < 4; ++i)
            #pragma unroll
            for (int j = 0; j < FN; ++j)
                acc[i][j] = __builtin_amdgcn_mfma_f32_16x16x32_bf16(af[i], bf[j], acc[i][j], 0, 0, 0);
    };
    auto step = [&](const unsigned short* cA, const unsigned short* cB,
                    unsigned short* nA, unsigned short* nB, int kn, bool do_stage) {
        if constexpr (NLD == 4) asm volatile("s_waitcnt vmcnt(4)" ::: "memory");
        else                    asm volatile("s_waitcnt vmcnt(3)" ::: "memory");
        __builtin_amdgcn_s_barrier();
        __builtin_amdgcn_sched_barrier(0);
        if (do_stage) stage(nA, nB, kn);
        compute(cA, cB);
    };

    stage(As0, Bs0, 0);
    stage(As1, Bs1, 32);

    // 32 K-steps: 10x3 + 2 tail. step s reads buf s%3, stages (s+2)%3.
    for (int kb = 0; kb < 30; kb += 3) {
        step(As0, Bs0, As2, Bs2, (kb + 2) * 32, true);
        step(As1, Bs1, As0, Bs0, (kb + 3) * 32, true);
        step(As2, Bs2, As1, Bs1, (kb + 4) * 32, true);
    }
    step(As0, Bs0, As2, Bs2, 0, false);                 // s=30: group31 stays in flight
    asm volatile("s_waitcnt vmcnt(0)" ::: "memory");    // s=31: drain last group
    __builtin_amdgcn_s_barrier();
    __builtin_amdgcn_sched_barrier(0);
    compute(As1, Bs1);

    if (mode == 1) {
        // rotary in registers: pair (acc[i][jc], acc[i][jc+FN/2]) = dims (d, d+32)
        #pragma unroll
        for (int i = 0; i < 4; ++i) {
            const int mb = m0 + wm * 64 + i * 16 + quad * 4;
            const int bb = mb >> 11, tb = mb & (T_ - 1);
            #pragma unroll
            for (int jc = 0; jc < FN / 2; ++jc) {
                const int n_lo = n0 + wn * (BN / 2) + jc * 16 + l16;
                const int h = n_lo >> 6, d = n_lo & 63;     // d < 32
                const float bv_lo = bias[n_lo], bv_hi = bias[n_lo + 32];
                unsigned short* po = outb + (((size_t)bb * H_ + h) * T_ + tb) * D_ + d;
                #pragma unroll
                for (int r = 0; r < 4; ++r) {
                    const float2 cs = trig[(tb + r) * 32 + d];
                    const float a = acc[i][jc][r] + bv_lo;
                    const float b = acc[i][jc + FN / 2][r] + bv_hi;
                    po[(size_t)r * D_]      = f2b((a * cs.x - b * cs.y) * rot_scale);
                    po[(size_t)r * D_ + 32] = f2b((b * cs.x + a * cs.y) * rot_scale);
                }
            }
        }
        return;
    }

    #pragma unroll
    for (int i = 0; i < 4; ++i) {
        const int mb = m0 + wm * 64 + i * 16 + quad * 4;
        #pragma unroll
        for (int j = 0; j < FN; ++j) {
            const int n = n0 + wn * (BN / 2) + j * 16 + l16;
            const float bv = bias[n];
            if (mode == 2) {
                // V^T: 4 consecutive t at fixed (h,d) -> one 8B store
                const int bb = mb >> 11, t = mb & (T_ - 1);
                const int h = n >> 6, d = n & 63;
                uint2 w;
                w.x = pack_bf16_rnd(acc[i][j][0] + bv, acc[i][j][1] + bv);
                w.y = pack_bf16_rnd(acc[i][j][2] + bv, acc[i][j][3] + bv);
                *reinterpret_cast<uint2*>(
                    outb + (((size_t)bb * H_ + h) * D_ + d) * T_ + t) = w;
            } else {
                #pragma unroll
                for (int r = 0; r < 4; ++r)
                    outf[(size_t)(mb + r) * C_ + n] = acc[i][j][r] + bv;
            }
        }
    }
}

// XCD-grouped decode (kept from R3 — FETCH 70.7 -> 30.8 MB confirmed):
// hw assigns XCD ~ dispatch_index % 8; give each XCD a CONTIGUOUS chunk of
// work so its A-row panels stay resident in its 4MB L2.
__global__ __launch_bounds__(256) void gemm_qkv(
    const unsigned short* __restrict__ A,
    const unsigned short* __restrict__ Wq, const unsigned short* __restrict__ Wk,
    const unsigned short* __restrict__ Wv,
    const float* __restrict__ bq, const float* __restrict__ bk,
    const float* __restrict__ bv, const float2* __restrict__ trig,
    unsigned short* __restrict__ Qo, unsigned short* __restrict__ Ko,
    unsigned short* __restrict__ Vto)
{
    const int lin = (int)blockIdx.x;        // 0..767
    const int g = lin & 7, slot = lin >> 3; // XCD, slot 0..95
    const int w = g * 96 + slot;            // contiguous chunk per XCD
    const int z = w >> 8, rem = w & 255;
    const int m0 = (rem >> 3) * 128, n0 = (rem & 7) * 128;

    const unsigned short* Bt = z == 0 ? Wq : z == 1 ? Wk : Wv;
    const float* bias = z == 0 ? bq : z == 1 ? bk : bv;
    unsigned short* outb = z == 0 ? Qo : z == 1 ? Ko : Vto;
    const float rs = z == 0 ? SCALE2 : 1.0f;
    gemm_core<128>(A, Bt, bias, trig, rs, nullptr, outb, z == 2 ? 2 : 1, m0, n0);
}

// proj: 128x128 tiles, 256 blocks = 1/CU, XCD-grouped.
__global__ __launch_bounds__(256) void gemm_proj(
    const unsigned short* __restrict__ A, const unsigned short* __restrict__ Bt,
    const float* __restrict__ bias, float* __restrict__ outf)
{
    const int lin = (int)blockIdx.x;        // 0..255
    const int g = lin & 7, slot = lin >> 3; // XCD, slot 0..31
    const int w = g * 32 + slot;
    const int m0 = (w >> 3) * 128, n0 = (w & 7) * 128;
    gemm_core<128>(A, Bt, bias, nullptr, 1.0f, outf, nullptr, 0, m0, n0);
}

// ---------------------------------------------------------------------------
// Flash attention, MFMA bf16 16x16x32, FIXED-SHIFT exp2 softmax.
// R10 (on the R8 base; R9 fused experiment reverted):
//  * grid 1024, ONE q-tile per block, heavy-first (qt = 31 - lin>>5).
//    LDS = 50.7 KB <= 53.3 KB -> 3 blocks/CU resident (12 waves/CU, was 8);
//    total work 16896 tile-units / 768 contexts = 22/context (was 33).
//    bh = lin&31 keeps the XCD mapping; __launch_bounds__(256,3).
//  * lgkm-only barrier: s_waitcnt lgkmcnt(0) + s_barrier instead of
//    __syncthreads() -> the K/V global prefetch issued this tile stays in
//    flight across the barrier (no vmcnt(0) drain; loads land at their
//    ds_write next tile). Correct: dbuf invariant only needs LDS visibility;
//    prefetch regs are wave-private. Barrier skipped after the last tile.
// R8 retained: XOR-swizzled K/V LDS (conflicts 4.87M->2.70M), bias in MFMA
// acc init, setprio, raw v_exp_f32, key-permuted P packing, ones-MFMA rowsum.
// ---------------------------------------------------------------------------
__device__ __forceinline__ int kv_swz(int row, int col8) {
    return row * 64 + ((col8 ^ ((row ^ (row >> 2)) & 7)) * 8);   // shorts
}

__global__ __launch_bounds__(256, 3) void flash_attn(
    const unsigned short* __restrict__ Q, const unsigned short* __restrict__ K,
    const unsigned short* __restrict__ Vt, const float* __restrict__ dtab,
    unsigned short* __restrict__ Y)
{
    __shared__ __align__(16) unsigned short Ks[2][64 * 64];
    __shared__ __align__(16) unsigned short Vs[2][64 * 64];
    __shared__ __align__(16) unsigned short Ps[4][16][72];
    __shared__ __align__(16) float bias_ls[64 + T_];

    const int lin = (int)blockIdx.x;           // 0..1023
    const int bh  = lin & 31;                  // XCD = bh&7, constant per head
    const int qt  = 31 - (lin >> 5);           // heavy q-tiles first (LPT)
    const int h = bh & (H_ - 1), b = bh >> 4;
    const int tid = threadIdx.x;
    const int wid = tid >> 6, lane = tid & 63;
    const int l16 = lane & 15, quad = lane >> 4;
    const size_t base = (size_t)bh * T_ * D_;
    const size_t vbase = (size_t)bh * D_ * T_;
    const int q0 = qt * 64;

    // shifted bias table: bias_ls[64+n] = dtab[h][n]; [0,64) = -inf
    if (tid < 64) bias_ls[tid] = -INFINITY;
    for (int ii = tid; ii < q0 + 64; ii += 256) bias_ls[64 + ii] = dtab[h * T_ + ii];

    bf16x8 ones;
    #pragma unroll
    for (int e = 0; e < 8; ++e) ones[e] = (short)0x3F80;   // bf16 1.0

    // staging coordinates (global side) + swizzled LDS offsets (hoisted)
    const int sr0 = tid >> 3,         sc80 = tid & 7;
    const int sr1 = (tid + 256) >> 3, sc81 = (tid + 256) & 7;
    const int wo0 = kv_swz(sr0, sc80), wo1 = kv_swz(sr1, sc81);
    const int sch0 = sc80 * 8, sch1 = sc81 * 8;   // global col in shorts

    // read offsets (hoisted): kf row = l16*4+c, vf row = c*16+l16, col8 = s*4+quad
    int kro[4][2], vro[4][2];
    #pragma unroll
    for (int c = 0; c < 4; ++c)
        #pragma unroll
        for (int s = 0; s < 2; ++s) {
            kro[c][s] = kv_swz(l16 * 4 + c, s * 4 + quad);
            vro[c][s] = kv_swz(c * 16 + l16, s * 4 + quad);
        }

    // prologue: tile0 -> regs -> LDS[0]; tile1 -> regs (in-bounds: T=2048)
    bf16x8 kr[2], vr[2];
    kr[0] = *reinterpret_cast<const bf16x8*>(K + base + (size_t)sr0 * D_ + sch0);
    kr[1] = *reinterpret_cast<const bf16x8*>(K + base + (size_t)sr1 * D_ + sch1);
    vr[0] = *reinterpret_cast<const bf16x8*>(Vt + vbase + (size_t)sr0 * T_ + sch0);
    vr[1] = *reinterpret_cast<const bf16x8*>(Vt + vbase + (size_t)sr1 * T_ + sch1);
    *reinterpret_cast<bf16x8*>(&Ks[0][wo0]) = kr[0];
    *reinterpret_cast<bf16x8*>(&Ks[0][wo1]) = kr[1];
    *reinterpret_cast<bf16x8*>(&Vs[0][wo0]) = vr[0];
    *reinterpret_cast<bf16x8*>(&Vs[0][wo1]) = vr[1];
    kr[0] = *reinterpret_cast<const bf16x8*>(K + base + (size_t)(64 + sr0) * D_ + sch0);
    kr[1] = *reinterpret_cast<const bf16x8*>(K + base + (size_t)(64 + sr1) * D_ + sch1);
    vr[0] = *reinterpret_cast<const bf16x8*>(Vt + vbase + (size_t)sr0 * T_ + 64 + sch0);
    vr[1] = *reinterpret_cast<const bf16x8*>(Vt + vbase + (size_t)sr1 * T_ + 64 + sch1);
    __syncthreads();   // bias fill + tile0 staging visible (full drain, once)

    const int arow = q0 + wid * 16 + l16;            // A-frag row (global)
    const int crow = q0 + wid * 16 + quad * 4;       // C-layout row base
    const int nbase = crow - l16 * 4;

    bf16x8 qf[2];
    qf[0] = *reinterpret_cast<const bf16x8*>(Q + base + (size_t)arow * D_ + quad * 8);
    qf[1] = *reinterpret_cast<const bf16x8*>(Q + base + (size_t)arow * D_ + 32 + quad * 8);

    f32x4 o[4], ol;
    #pragma unroll
    for (int c = 0; c < 4; ++c) o[c] = (f32x4){0.f, 0.f, 0.f, 0.f};
    ol = (f32x4){0.f, 0.f, 0.f, 0.f};

    for (int kt = 0; kt <= qt; ++kt) {
        const int j0 = kt * 64;
        const int cur = kt & 1, nxt = cur ^ 1;

        // stage tile kt+1 (regs loaded one iteration ago) into buf[nxt]
        if (kt < qt) {
            *reinterpret_cast<bf16x8*>(&Ks[nxt][wo0]) = kr[0];
            *reinterpret_cast<bf16x8*>(&Ks[nxt][wo1]) = kr[1];
            *reinterpret_cast<bf16x8*>(&Vs[nxt][wo0]) = vr[0];
            *reinterpret_cast<bf16x8*>(&Vs[nxt][wo1]) = vr[1];
        }
        // issue prefetch of tile kt+2 (consumed by the write at kt+1)
        if (kt < qt - 1) {
            const int jn = j0 + 128;
            kr[0] = *reinterpret_cast<const bf16x8*>(K + base + (size_t)(jn + sr0) * D_ + sch0);
            kr[1] = *reinterpret_cast<const bf16x8*>(K + base + (size_t)(jn + sr1) * D_ + sch1);
            vr[0] = *reinterpret_cast<const bf16x8*>(Vt + vbase + (size_t)sr0 * T_ + jn + sch0);
            vr[1] = *reinterpret_cast<const bf16x8*>(Vt + vbase + (size_t)sr1 * T_ + jn + sch1);
        }

        // per-lane bias window: bias_ls[64+d0+k], k in [-4,3], d0 % 4 == 0
        const int d0 = nbase - j0;
        const f32x4 blo = *reinterpret_cast<const f32x4*>(&bias_ls[60 + d0]);
        const f32x4 bhi = *reinterpret_cast<const f32x4*>(&bias_ls[64 + d0]);

        // ---- S = Q K^T + bias, bias in accumulator init ----
        f32x4 sc[4];
        #pragma unroll
        for (int c = 0; c < 4; ++c) {
            #pragma unroll
            for (int r = 0; r < 4; ++r)
                sc[c][r] = (r >= c) ? bhi[r - c] : blo[4 + r - c];
        }
        __builtin_amdgcn_s_setprio(1);
        #pragma unroll
        for (int c = 0; c < 4; ++c) {
            #pragma unroll
            for (int s = 0; s < 2; ++s) {
                bf16x8 kf = *reinterpret_cast<const bf16x8*>(&Ks[cur][kro[c][s]]);
                sc[c] = __builtin_amdgcn_mfma_f32_16x16x32_bf16(qf[s], kf, sc[c], 0, 0, 0);
            }
        }
        __builtin_amdgcn_s_setprio(0);

        // ---- P = exp2(S); fixed shift, raw v_exp_f32 ----
        #pragma unroll
        for (int r = 0; r < 4; ++r) {
            const float p0 = __builtin_amdgcn_exp2f(sc[0][r]);
            const float p1 = __builtin_amdgcn_exp2f(sc[1][r]);
            const float p2 = __builtin_amdgcn_exp2f(sc[2][r]);
            const float p3 = __builtin_amdgcn_exp2f(sc[3][r]);
            uint2 w;
            w.x = pack_bf16_rnd(p0, p1);
            w.y = pack_bf16_rnd(p2, p3);
            *reinterpret_cast<uint2*>(&Ps[wid][quad * 4 + r][l16 * 4]) = w;
        }

        // ---- O += P V; row-sum via ones-column MFMA ----
        __builtin_amdgcn_s_setprio(1);
        #pragma unroll
        for (int s = 0; s < 2; ++s) {
            bf16x8 pf = *reinterpret_cast<const bf16x8*>(&Ps[wid][l16][s * 32 + quad * 8]);
            #pragma unroll
            for (int c = 0; c < 4; ++c) {
                bf16x8 vf = *reinterpret_cast<const bf16x8*>(&Vs[cur][vro[c][s]]);
                o[c] = __builtin_amdgcn_mfma_f32_16x16x32_bf16(pf, vf, o[c], 0, 0, 0);
            }
            ol = __builtin_amdgcn_mfma_f32_16x16x32_bf16(pf, ones, ol, 0, 0, 0);
        }
        __builtin_amdgcn_s_setprio(0);

        // lgkm-only barrier: LDS visibility without draining the prefetch
        if (kt < qt) {
            asm volatile("s_waitcnt lgkmcnt(0)" ::: "memory");
            __builtin_amdgcn_s_barrier();
            __builtin_amdgcn_sched_barrier(0);
        }
    }

    // ---- epilogue: normalize and write Y [B,T,C] bf16 ----
    #pragma unroll
    for (int r = 0; r < 4; ++r) {
        const int i = crow + r;
        const float invl = 1.0f / ol[r];
        #pragma unroll
        for (int c = 0; c < 4; ++c)
            Y[((size_t)b * T_ + i) * C_ + h * D_ + c * 16 + l16] = f2b(o[c][r] * invl);
    }
}

// ---------------------------------------------------------------------------
extern "C" void kernel_launch(void* const* d_in, const int* in_sizes, int n_in,
                              void* d_out, int out_size, void* d_ws, size_t ws_size,
                              hipStream_t stream)
{
    const float* x   = (const float*)d_in[0];
    const float* Wq  = (const float*)d_in[1];
    const float* bq  = (const float*)d_in[2];
    const float* Wk  = (const float*)d_in[3];
    const float* bk  = (const float*)d_in[4];
    const float* Wv  = (const float*)d_in[5];
    const float* bv  = (const float*)d_in[6];
    const float* Wp  = (const float*)d_in[7];
    const float* bp  = (const float*)d_in[8];
    const float* tbl = (const float*)d_in[9];
    float* out = (float*)d_out;

    const size_t n1 = (size_t)B_ * H_ * T_ * D_;       // 4,194,304
    const size_t nW = (size_t)C_ * C_;                 // 1,048,576
    unsigned short* xb  = (unsigned short*)d_ws;       // 8 MB
    unsigned short* Wqt = xb + (size_t)M_ * K_;        // 2 MB each
    unsigned short* Wkt = Wqt + nW;
    unsigned short* Wvt = Wkt + nW;
    unsigned short* Wpt = Wvt + nW;
    unsigned short* Qb  = Wpt + nW;                    // 8 MB each
    unsigned short* Kb  = Qb + n1;
    unsigned short* Vtb = Kb + n1;                     // V^T, written by gemm_qkv
    unsigned short* Yb  = Vtb + n1;
    float* dtab = (float*)(Yb + n1);                   // 128 KB
    float2* trig = (float2*)(dtab + H_ * T_);          // 512 KB (~48.6 MB total)

    const dim3 blk(256);

    prep<<<dim3(3328), blk, 0, stream>>>(x, Wq, Wk, Wv, Wp, tbl,
                                         xb, Wqt, Wkt, Wvt, Wpt, dtab, trig);

    gemm_qkv<<<dim3(768), blk, 0, stream>>>(
        xb, Wqt, Wkt, Wvt, bq, bk, bv, trig, Qb, Kb, Vtb);

    flash_attn<<<dim3(1024), blk, 0, stream>>>(Qb, Kb, Vtb, dtab, Yb);

    gemm_proj<<<dim3(256), blk, 0, stream>>>(Yb, Wpt, bp, out);
}

// Round 11
// 186.417 us; speedup vs baseline: 2.5860x; 1.0102x over previous
//
#include <hip/hip_runtime.h>
#include <hip/hip_bf16.h>
#include <math.h>

#define B_ 2
#define T_ 2048
#define C_ 1024
#define H_ 16
#define D_ 64
#define M_ (B_ * T_)   // 4096
#define K_ 1024

// 0.125 * log2(e): folds the 1/sqrt(64) softmax scale into exp2-domain
#define SCALE2 0.18033688011112043f

typedef short bf16x8 __attribute__((ext_vector_type(8)));
typedef float f32x4  __attribute__((ext_vector_type(4)));
typedef unsigned int u32;

__device__ __forceinline__ unsigned short f2b(float f) {
    __hip_bfloat16 h = __float2bfloat16(f);
    return *reinterpret_cast<unsigned short*>(&h);
}
// pack hi16(a),hi16(b) -> dword [b_hi:a_hi] with round-half-up (+0x8000)
__device__ __forceinline__ u32 pack_bf16_rnd(float a, float b) {
    const u32 au = __float_as_uint(a) + 0x8000u;
    const u32 bu = __float_as_uint(b) + 0x8000u;
    return __builtin_amdgcn_perm(bu, au, 0x07060302u);
}
__device__ __forceinline__ void load_lds16(const void* g, void* l) {
    __builtin_amdgcn_global_load_lds(
        (const __attribute__((address_space(1))) u32*)g,
        (__attribute__((address_space(3))) u32*)l, 16, 0, 0);
}

// ---------------------------------------------------------------------------
// Merged prep kernel (one launch instead of three):
//   bx <  2048 : convert x fp32 -> bf16
//   bx <  3072 : convert + transpose W[z] (64x64 tiles)
//   else       : distance-bias table (exp2 domain) + rotary trig table
// R11: transpose tile stride 72 -> 66. Old gather bank = (8e+nc) mod 64 was
// kc-independent -> 8-way conflict on the 8 column reads; 66 === 2 mod 64
// gives (16a+2e+nc) -> exact 2-way (free, m136) and keeps c*2 multiple-of-8
// so the 4-short tile writes stay b64-vectorizable.
// ---------------------------------------------------------------------------
__global__ __launch_bounds__(256) void prep(
    const float* __restrict__ x,
    const float* __restrict__ W0, const float* __restrict__ W1,
    const float* __restrict__ W2, const float* __restrict__ W3,
    const float* __restrict__ tbl,
    unsigned short* __restrict__ xb,
    unsigned short* __restrict__ T0, unsigned short* __restrict__ T1,
    unsigned short* __restrict__ T2, unsigned short* __restrict__ T3,
    float* __restrict__ dtab, float2* __restrict__ trig)
{
    __shared__ __align__(16) unsigned short tile[64][66];
    const int bx = blockIdx.x;
    const int tid = threadIdx.x;

    if (bx < 2048) {
        const int idx = bx * 256 + tid;
        const float4 a = reinterpret_cast<const float4*>(x)[idx * 2];
        const float4 b = reinterpret_cast<const float4*>(x)[idx * 2 + 1];
        unsigned short t[8] = {f2b(a.x), f2b(a.y), f2b(a.z), f2b(a.w),
                               f2b(b.x), f2b(b.y), f2b(b.z), f2b(b.w)};
        reinterpret_cast<bf16x8*>(xb)[idx] = *reinterpret_cast<const bf16x8*>(t);
    } else if (bx < 3072) {
        const int w = bx - 2048;               // 0..1023
        const int z = w >> 8;                  // which W
        const int rem = w & 255;
        const int k0 = (rem & 15) * 64, n0 = (rem >> 4) * 64;
        const float* W = z == 0 ? W0 : z == 1 ? W1 : z == 2 ? W2 : W3;
        unsigned short* Wt = z == 0 ? T0 : z == 1 ? T1 : z == 2 ? T2 : T3;

        #pragma unroll
        for (int it = 0; it < 4; ++it) {
            const int idx = it * 256 + tid;
            const int r = idx >> 4, c = (idx & 15) * 4;
            const float4 w4 = *reinterpret_cast<const float4*>(W + (size_t)(k0 + r) * C_ + n0 + c);
            tile[r][c + 0] = f2b(w4.x); tile[r][c + 1] = f2b(w4.y);
            tile[r][c + 2] = f2b(w4.z); tile[r][c + 3] = f2b(w4.w);
        }
        __syncthreads();
        #pragma unroll
        for (int it = 0; it < 2; ++it) {
            const int idx = it * 256 + tid;
            const int nc = idx >> 3, kc = (idx & 7) * 8;
            unsigned short tmp[8];
            #pragma unroll
            for (int e = 0; e < 8; ++e) tmp[e] = tile[kc + e][nc];
            *reinterpret_cast<bf16x8*>(Wt + (size_t)(n0 + nc) * K_ + k0 + kc) =
                *reinterpret_cast<const bf16x8*>(tmp);
        }
    } else {
        const int idx = (bx - 3072) * 256 + tid;   // 0..65535
        if (idx < H_ * T_) {
            const int h = idx >> 11, n = idx & (T_ - 1);
            int bucket;
            if (n < 16) bucket = n;
            else {
                int vb = 16 + (int)(log2f((float)n * 0.0625f) * (16.0f / 3.0f));
                bucket = vb < 31 ? vb : 31;
            }
            dtab[idx] = tbl[bucket * H_ + h] * SCALE2;
        }
        const int t = idx >> 5, j = idx & 31;
        // inv_freq = 10000^{-j/32} = 2^{-j*log2(10000)/32}
        const float inv = exp2f(-(float)j * (13.287712379549449f / 32.0f));
        const float ang = (float)t * inv;
        trig[idx] = make_float2(cosf(ang), sinf(ang));
    }
}

// ---------------------------------------------------------------------------
// MFMA GEMM core: counted-vmcnt 3-buffer pipeline (T4, R5) + R11 LDS swizzle.
// R11: the af/bf ds_read_b128 had an 8-way bank conflict (row = base+l16 ->
// bank-start 16*l16 mod 32 = {0,16} for 16 lanes). Fix per rule #21
// (global_load_lds writes linearly): pre-swizzle the GLOBAL source column
// (ch ^= f(row), f(row) = (row>>1)&3 = (idx>>3)&3) and XOR the read slot
// (cs = (quad ^ ((l16>>1)&3))*8). Full-wave bank table: 32 banks covered,
// exactly 2 lanes/bank = free. Global coalescing unchanged (same 64B row,
// permuted within). Numerics identical.
// mode 0: fp32 row-major [M,C]; mode 1: rotary+scatter bf16 (Q,K);
// mode 2: bf16 V^T [B,H,D,T] packed b64 stores (V)
// ---------------------------------------------------------------------------
template<int BN>
__device__ __forceinline__ void gemm_core(
    const unsigned short* __restrict__ A, const unsigned short* __restrict__ Bt,
    const float* __restrict__ bias, const float2* __restrict__ trig,
    float rot_scale, float* __restrict__ outf,
    unsigned short* __restrict__ outb, int mode, int m0, int n0)
{
    constexpr int FN  = BN / 32;    // n-frags per wave (4 for BN=128, 2 for BN=64)
    constexpr int BCH = BN / 64;    // B stage chunks per thread
    constexpr int NLD = 2 + BCH;    // global_load_lds per thread per stage
    __shared__ __align__(16) unsigned short As0[128 * 32];
    __shared__ __align__(16) unsigned short As1[128 * 32];
    __shared__ __align__(16) unsigned short As2[128 * 32];
    __shared__ __align__(16) unsigned short Bs0[BN * 32];
    __shared__ __align__(16) unsigned short Bs1[BN * 32];
    __shared__ __align__(16) unsigned short Bs2[BN * 32];

    const int tid = threadIdx.x;
    const int wid = tid >> 6, lane = tid & 63;
    const int l16 = lane & 15, quad = lane >> 4;
    const int wm = wid >> 1, wn = wid & 1;
    // R11: swizzled 16B-slot offset for fragment reads (hoisted, loop-inv)
    const int cs = ((quad ^ ((l16 >> 1) & 3)) * 8);

    f32x4 acc[4][FN];
    #pragma unroll
    for (int i = 0; i < 4; ++i)
        #pragma unroll
        for (int j = 0; j < FN; ++j) acc[i][j] = (f32x4){0.f, 0.f, 0.f, 0.f};

    // global_load_lds: LDS dest = wave-uniform base + lane*16 (HW constraint)
    // -> LDS layout stays linear; swizzle is applied to the GLOBAL column.
    auto stage = [&](unsigned short* Asb, unsigned short* Bsb, int k0) {
        #pragma unroll
        for (int it = 0; it < 2; ++it) {
            const int idx = it * 256 + tid;
            const int row = idx >> 2;
            const int ch = (((idx & 3) ^ ((idx >> 3) & 3)) * 8);
            load_lds16(A + (size_t)(m0 + row) * K_ + k0 + ch,
                       (char*)Asb + it * 4096 + wid * 1024);
        }
        #pragma unroll
        for (int it = 0; it < BCH; ++it) {
            const int idx = it * 256 + tid;
            const int row = idx >> 2;
            const int ch = (((idx & 3) ^ ((idx >> 3) & 3)) * 8);
            load_lds16(Bt + (size_t)(n0 + row) * K_ + k0 + ch,
                       (char*)Bsb + it * 4096 + wid * 1024);
        }
    };
    auto compute = [&](const unsigned short* Asb, const unsigned short* Bsb) {
        bf16x8 af[4], bf[FN];
        #pragma unroll
        for (int i = 0; i < 4; ++i)
            af[i] = *reinterpret_cast<const bf16x8*>(&Asb[(wm * 64 + i * 16 + l16) * 32 + cs]);
        #pragma unroll
        for (int j = 0; j < FN; ++j)
            bf[j] = *reinterpret_cast<const bf16x8*>(&Bsb[(wn * (BN / 2) + j * 16 + l16) * 32 + cs]);
        #pragma unroll
        for (int i = 0; i < 4; ++i)
            #pragma unroll
            for (int j = 0; j < FN; ++j)
                acc[i][j] = __builtin_amdgcn_mfma_f32_16x16x32_bf16(af[i], bf[j], acc[i][j], 0, 0, 0);
    };
    auto step = [&](const unsigned short* cA, const unsigned short* cB,
                    unsigned short* nA, unsigned short* nB, int kn, bool do_stage) {
        if constexpr (NLD == 4) asm volatile("s_waitcnt vmcnt(4)" ::: "memory");
        else                    asm volatile("s_waitcnt vmcnt(3)" ::: "memory");
        __builtin_amdgcn_s_barrier();
        __builtin_amdgcn_sched_barrier(0);
        if (do_stage) stage(nA, nB, kn);
        compute(cA, cB);
    };

    stage(As0, Bs0, 0);
    stage(As1, Bs1, 32);

    // 32 K-steps: 10x3 + 2 tail. step s reads buf s%3, stages (s+2)%3.
    for (int kb = 0; kb < 30; kb += 3) {
        step(As0, Bs0, As2, Bs2, (kb + 2) * 32, true);
        step(As1, Bs1, As0, Bs0, (kb + 3) * 32, true);
        step(As2, Bs2, As1, Bs1, (kb + 4) * 32, true);
    }
    step(As0, Bs0, As2, Bs2, 0, false);                 // s=30: group31 stays in flight
    asm volatile("s_waitcnt vmcnt(0)" ::: "memory");    // s=31: drain last group
    __builtin_amdgcn_s_barrier();
    __builtin_amdgcn_sched_barrier(0);
    compute(As1, Bs1);

    if (mode == 1) {
        // rotary in registers: pair (acc[i][jc], acc[i][jc+FN/2]) = dims (d, d+32)
        #pragma unroll
        for (int i = 0; i < 4; ++i) {
            const int mb = m0 + wm * 64 + i * 16 + quad * 4;
            const int bb = mb >> 11, tb = mb & (T_ - 1);
            #pragma unroll
            for (int jc = 0; jc < FN / 2; ++jc) {
                const int n_lo = n0 + wn * (BN / 2) + jc * 16 + l16;
                const int h = n_lo >> 6, d = n_lo & 63;     // d < 32
                const float bv_lo = bias[n_lo], bv_hi = bias[n_lo + 32];
                unsigned short* po = outb + (((size_t)bb * H_ + h) * T_ + tb) * D_ + d;
                #pragma unroll
                for (int r = 0; r < 4; ++r) {
                    const float2 cs2 = trig[(tb + r) * 32 + d];
                    const float a = acc[i][jc][r] + bv_lo;
                    const float b = acc[i][jc + FN / 2][r] + bv_hi;
                    po[(size_t)r * D_]      = f2b((a * cs2.x - b * cs2.y) * rot_scale);
                    po[(size_t)r * D_ + 32] = f2b((b * cs2.x + a * cs2.y) * rot_scale);
                }
            }
        }
        return;
    }

    #pragma unroll
    for (int i = 0; i < 4; ++i) {
        const int mb = m0 + wm * 64 + i * 16 + quad * 4;
        #pragma unroll
        for (int j = 0; j < FN; ++j) {
            const int n = n0 + wn * (BN / 2) + j * 16 + l16;
            const float bv = bias[n];
            if (mode == 2) {
                // V^T: 4 consecutive t at fixed (h,d) -> one 8B store
                const int bb = mb >> 11, t = mb & (T_ - 1);
                const int h = n >> 6, d = n & 63;
                uint2 w;
                w.x = pack_bf16_rnd(acc[i][j][0] + bv, acc[i][j][1] + bv);
                w.y = pack_bf16_rnd(acc[i][j][2] + bv, acc[i][j][3] + bv);
                *reinterpret_cast<uint2*>(
                    outb + (((size_t)bb * H_ + h) * D_ + d) * T_ + t) = w;
            } else {
                #pragma unroll
                for (int r = 0; r < 4; ++r)
                    outf[(size_t)(mb + r) * C_ + n] = acc[i][j][r] + bv;
            }
        }
    }
}

// XCD-grouped decode (kept from R3 — FETCH 70.7 -> 30.8 MB confirmed):
// hw assigns XCD ~ dispatch_index % 8; give each XCD a CONTIGUOUS chunk of
// work so its A-row panels stay resident in its 4MB L2.
__global__ __launch_bounds__(256) void gemm_qkv(
    const unsigned short* __restrict__ A,
    const unsigned short* __restrict__ Wq, const unsigned short* __restrict__ Wk,
    const unsigned short* __restrict__ Wv,
    const float* __restrict__ bq, const float* __restrict__ bk,
    const float* __restrict__ bv, const float2* __restrict__ trig,
    unsigned short* __restrict__ Qo, unsigned short* __restrict__ Ko,
    unsigned short* __restrict__ Vto)
{
    const int lin = (int)blockIdx.x;        // 0..767
    const int g = lin & 7, slot = lin >> 3; // XCD, slot 0..95
    const int w = g * 96 + slot;            // contiguous chunk per XCD
    const int z = w >> 8, rem = w & 255;
    const int m0 = (rem >> 3) * 128, n0 = (rem & 7) * 128;

    const unsigned short* Bt = z == 0 ? Wq : z == 1 ? Wk : Wv;
    const float* bias = z == 0 ? bq : z == 1 ? bk : bv;
    unsigned short* outb = z == 0 ? Qo : z == 1 ? Ko : Vto;
    const float rs = z == 0 ? SCALE2 : 1.0f;
    gemm_core<128>(A, Bt, bias, trig, rs, nullptr, outb, z == 2 ? 2 : 1, m0, n0);
}

// R11: proj back to 128x64 tiles -> 512 blocks = 2/CU (R5-vs-R7 evidence:
// BN=64 proj was ~2 µs better; 1 block/CU leaves latency exposed).
__global__ __launch_bounds__(256) void gemm_proj(
    const unsigned short* __restrict__ A, const unsigned short* __restrict__ Bt,
    const float* __restrict__ bias, float* __restrict__ outf)
{
    const int lin = (int)blockIdx.x;        // 0..511
    const int g = lin & 7, slot = lin >> 3; // XCD, slot 0..63
    const int w = g * 64 + slot;
    const int m0 = (w >> 4) * 128, n0 = (w & 15) * 64;
    gemm_core<64>(A, Bt, bias, nullptr, 1.0f, outf, nullptr, 0, m0, n0);
}

// ---------------------------------------------------------------------------
// Flash attention, MFMA bf16 16x16x32, FIXED-SHIFT exp2 softmax.
// (frozen at R10: grid 1024 one-q-tile-per-block heavy-first, 3 blocks/CU,
// lgkm-only barrier keeping K/V prefetch in flight, XOR-swizzled K/V LDS,
// bias in MFMA acc init, setprio, raw v_exp_f32, key-permuted P packing,
// ones-MFMA rowsum.)
// ---------------------------------------------------------------------------
__device__ __forceinline__ int kv_swz(int row, int col8) {
    return row * 64 + ((col8 ^ ((row ^ (row >> 2)) & 7)) * 8);   // shorts
}

__global__ __launch_bounds__(256, 3) void flash_attn(
    const unsigned short* __restrict__ Q, const unsigned short* __restrict__ K,
    const unsigned short* __restrict__ Vt, const float* __restrict__ dtab,
    unsigned short* __restrict__ Y)
{
    __shared__ __align__(16) unsigned short Ks[2][64 * 64];
    __shared__ __align__(16) unsigned short Vs[2][64 * 64];
    __shared__ __align__(16) unsigned short Ps[4][16][72];
    __shared__ __align__(16) float bias_ls[64 + T_];

    const int lin = (int)blockIdx.x;           // 0..1023
    const int bh  = lin & 31;                  // XCD = bh&7, constant per head
    const int qt  = 31 - (lin >> 5);           // heavy q-tiles first (LPT)
    const int h = bh & (H_ - 1), b = bh >> 4;
    const int tid = threadIdx.x;
    const int wid = tid >> 6, lane = tid & 63;
    const int l16 = lane & 15, quad = lane >> 4;
    const size_t base = (size_t)bh * T_ * D_;
    const size_t vbase = (size_t)bh * D_ * T_;
    const int q0 = qt * 64;

    // shifted bias table: bias_ls[64+n] = dtab[h][n]; [0,64) = -inf
    if (tid < 64) bias_ls[tid] = -INFINITY;
    for (int ii = tid; ii < q0 + 64; ii += 256) bias_ls[64 + ii] = dtab[h * T_ + ii];

    bf16x8 ones;
    #pragma unroll
    for (int e = 0; e < 8; ++e) ones[e] = (short)0x3F80;   // bf16 1.0

    // staging coordinates (global side) + swizzled LDS offsets (hoisted)
    const int sr0 = tid >> 3,         sc80 = tid & 7;
    const int sr1 = (tid + 256) >> 3, sc81 = (tid + 256) & 7;
    const int wo0 = kv_swz(sr0, sc80), wo1 = kv_swz(sr1, sc81);
    const int sch0 = sc80 * 8, sch1 = sc81 * 8;   // global col in shorts

    // read offsets (hoisted): kf row = l16*4+c, vf row = c*16+l16, col8 = s*4+quad
    int kro[4][2], vro[4][2];
    #pragma unroll
    for (int c = 0; c < 4; ++c)
        #pragma unroll
        for (int s = 0; s < 2; ++s) {
            kro[c][s] = kv_swz(l16 * 4 + c, s * 4 + quad);
            vro[c][s] = kv_swz(c * 16 + l16, s * 4 + quad);
        }

    // prologue: tile0 -> regs -> LDS[0]; tile1 -> regs (in-bounds: T=2048)
    bf16x8 kr[2], vr[2];
    kr[0] = *reinterpret_cast<const bf16x8*>(K + base + (size_t)sr0 * D_ + sch0);
    kr[1] = *reinterpret_cast<const bf16x8*>(K + base + (size_t)sr1 * D_ + sch1);
    vr[0] = *reinterpret_cast<const bf16x8*>(Vt + vbase + (size_t)sr0 * T_ + sch0);
    vr[1] = *reinterpret_cast<const bf16x8*>(Vt + vbase + (size_t)sr1 * T_ + sch1);
    *reinterpret_cast<bf16x8*>(&Ks[0][wo0]) = kr[0];
    *reinterpret_cast<bf16x8*>(&Ks[0][wo1]) = kr[1];
    *reinterpret_cast<bf16x8*>(&Vs[0][wo0]) = vr[0];
    *reinterpret_cast<bf16x8*>(&Vs[0][wo1]) = vr[1];
    kr[0] = *reinterpret_cast<const bf16x8*>(K + base + (size_t)(64 + sr0) * D_ + sch0);
    kr[1] = *reinterpret_cast<const bf16x8*>(K + base + (size_t)(64 + sr1) * D_ + sch1);
    vr[0] = *reinterpret_cast<const bf16x8*>(Vt + vbase + (size_t)sr0 * T_ + 64 + sch0);
    vr[1] = *reinterpret_cast<const bf16x8*>(Vt + vbase + (size_t)sr1 * T_ + 64 + sch1);
    __syncthreads();   // bias fill + tile0 staging visible (full drain, once)

    const int arow = q0 + wid * 16 + l16;            // A-frag row (global)
    const int crow = q0 + wid * 16 + quad * 4;       // C-layout row base
    const int nbase = crow - l16 * 4;

    bf16x8 qf[2];
    qf[0] = *reinterpret_cast<const bf16x8*>(Q + base + (size_t)arow * D_ + quad * 8);
    qf[1] = *reinterpret_cast<const bf16x8*>(Q + base + (size_t)arow * D_ + 32 + quad * 8);

    f32x4 o[4], ol;
    #pragma unroll
    for (int c = 0; c < 4; ++c) o[c] = (f32x4){0.f, 0.f, 0.f, 0.f};
    ol = (f32x4){0.f, 0.f, 0.f, 0.f};

    for (int kt = 0; kt <= qt; ++kt) {
        const int j0 = kt * 64;
        const int cur = kt & 1, nxt = cur ^ 1;

        // stage tile kt+1 (regs loaded one iteration ago) into buf[nxt]
        if (kt < qt) {
            *reinterpret_cast<bf16x8*>(&Ks[nxt][wo0]) = kr[0];
            *reinterpret_cast<bf16x8*>(&Ks[nxt][wo1]) = kr[1];
            *reinterpret_cast<bf16x8*>(&Vs[nxt][wo0]) = vr[0];
            *reinterpret_cast<bf16x8*>(&Vs[nxt][wo1]) = vr[1];
        }
        // issue prefetch of tile kt+2 (consumed by the write at kt+1)
        if (kt < qt - 1) {
            const int jn = j0 + 128;
            kr[0] = *reinterpret_cast<const bf16x8*>(K + base + (size_t)(jn + sr0) * D_ + sch0);
            kr[1] = *reinterpret_cast<const bf16x8*>(K + base + (size_t)(jn + sr1) * D_ + sch1);
            vr[0] = *reinterpret_cast<const bf16x8*>(Vt + vbase + (size_t)sr0 * T_ + jn + sch0);
            vr[1] = *reinterpret_cast<const bf16x8*>(Vt + vbase + (size_t)sr1 * T_ + jn + sch1);
        }

        // per-lane bias window: bias_ls[64+d0+k], k in [-4,3], d0 % 4 == 0
        const int d0 = nbase - j0;
        const f32x4 blo = *reinterpret_cast<const f32x4*>(&bias_ls[60 + d0]);
        const f32x4 bhi = *reinterpret_cast<const f32x4*>(&bias_ls[64 + d0]);

        // ---- S = Q K^T + bias, bias in accumulator init ----
        f32x4 sc[4];
        #pragma unroll
        for (int c = 0; c < 4; ++c) {
            #pragma unroll
            for (int r = 0; r < 4; ++r)
                sc[c][r] = (r >= c) ? bhi[r - c] : blo[4 + r - c];
        }
        __builtin_amdgcn_s_setprio(1);
        #pragma unroll
        for (int c = 0; c < 4; ++c) {
            #pragma unroll
            for (int s = 0; s < 2; ++s) {
                bf16x8 kf = *reinterpret_cast<const bf16x8*>(&Ks[cur][kro[c][s]]);
                sc[c] = __builtin_amdgcn_mfma_f32_16x16x32_bf16(qf[s], kf, sc[c], 0, 0, 0);
            }
        }
        __builtin_amdgcn_s_setprio(0);

        // ---- P = exp2(S); fixed shift, raw v_exp_f32 ----
        #pragma unroll
        for (int r = 0; r < 4; ++r) {
            const float p0 = __builtin_amdgcn_exp2f(sc[0][r]);
            const float p1 = __builtin_amdgcn_exp2f(sc[1][r]);
            const float p2 = __builtin_amdgcn_exp2f(sc[2][r]);
            const float p3 = __builtin_amdgcn_exp2f(sc[3][r]);
            uint2 w;
            w.x = pack_bf16_rnd(p0, p1);
            w.y = pack_bf16_rnd(p2, p3);
            *reinterpret_cast<uint2*>(&Ps[wid][quad * 4 + r][l16 * 4]) = w;
        }

        // ---- O += P V; row-sum via ones-column MFMA ----
        __builtin_amdgcn_s_setprio(1);
        #pragma unroll
        for (int s = 0; s < 2; ++s) {
            bf16x8 pf = *reinterpret_cast<const bf16x8*>(&Ps[wid][l16][s * 32 + quad * 8]);
            #pragma unroll
            for (int c = 0; c < 4; ++c) {
                bf16x8 vf = *reinterpret_cast<const bf16x8*>(&Vs[cur][vro[c][s]]);
                o[c] = __builtin_amdgcn_mfma_f32_16x16x32_bf16(pf, vf, o[c], 0, 0, 0);
            }
            ol = __builtin_amdgcn_mfma_f32_16x16x32_bf16(pf, ones, ol, 0, 0, 0);
        }
        __builtin_amdgcn_s_setprio(0);

        // lgkm-only barrier: LDS visibility without draining the prefetch
        if (kt < qt) {
            asm volatile("s_waitcnt lgkmcnt(0)" ::: "memory");
            __builtin_amdgcn_s_barrier();
            __builtin_amdgcn_sched_barrier(0);
        }
    }

    // ---- epilogue: normalize and write Y [B,T,C] bf16 ----
    #pragma unroll
    for (int r = 0; r < 4; ++r) {
        const int i = crow + r;
        const float invl = 1.0f / ol[r];
        #pragma unroll
        for (int c = 0; c < 4; ++c)
            Y[((size_t)b * T_ + i) * C_ + h * D_ + c * 16 + l16] = f2b(o[c][r] * invl);
    }
}

// ---------------------------------------------------------------------------
extern "C" void kernel_launch(void* const* d_in, const int* in_sizes, int n_in,
                              void* d_out, int out_size, void* d_ws, size_t ws_size,
                              hipStream_t stream)
{
    const float* x   = (const float*)d_in[0];
    const float* Wq  = (const float*)d_in[1];
    const float* bq  = (const float*)d_in[2];
    const float* Wk  = (const float*)d_in[3];
    const float* bk  = (const float*)d_in[4];
    const float* Wv  = (const float*)d_in[5];
    const float* bv  = (const float*)d_in[6];
    const float* Wp  = (const float*)d_in[7];
    const float* bp  = (const float*)d_in[8];
    const float* tbl = (const float*)d_in[9];
    float* out = (float*)d_out;

    const size_t n1 = (size_t)B_ * H_ * T_ * D_;       // 4,194,304
    const size_t nW = (size_t)C_ * C_;                 // 1,048,576
    unsigned short* xb  = (unsigned short*)d_ws;       // 8 MB
    unsigned short* Wqt = xb + (size_t)M_ * K_;        // 2 MB each
    unsigned short* Wkt = Wqt + nW;
    unsigned short* Wvt = Wkt + nW;
    unsigned short* Wpt = Wvt + nW;
    unsigned short* Qb  = Wpt + nW;                    // 8 MB each
    unsigned short* Kb  = Qb + n1;
    unsigned short* Vtb = Kb + n1;                     // V^T, written by gemm_qkv
    unsigned short* Yb  = Vtb + n1;
    float* dtab = (float*)(Yb + n1);                   // 128 KB
    float2* trig = (float2*)(dtab + H_ * T_);          // 512 KB (~48.6 MB total)

    const dim3 blk(256);

    prep<<<dim3(3328), blk, 0, stream>>>(x, Wq, Wk, Wv, Wp, tbl,
                                         xb, Wqt, Wkt, Wvt, Wpt, dtab, trig);

    gemm_qkv<<<dim3(768), blk, 0, stream>>>(
        xb, Wqt, Wkt, Wvt, bq, bk, bv, trig, Qb, Kb, Vtb);

    flash_attn<<<dim3(1024), blk, 0, stream>>>(Qb, Kb, Vtb, dtab, Yb);

    gemm_proj<<<dim3(512), blk, 0, stream>>>(Yb, Wpt, bp, out);
}